// Round 10
// baseline (144.140 us; speedup 1.0000x reference)
//
#include <hip/hip_runtime.h>
#include <hip/hip_bf16.h>

// Dims (fixed by the problem)
#define B_   8
#define L_   256
#define D_   32
#define E_   128
#define H_   8
#define Q_   128
#define HID_ 256

__device__ __forceinline__ unsigned pack_bf2(float a, float b)
{
    __hip_bfloat16 ha = __float2bfloat16(a);
    __hip_bfloat16 hb = __float2bfloat16(b);
    unsigned short ua = *reinterpret_cast<unsigned short*>(&ha);
    unsigned short ub = *reinterpret_cast<unsigned short*>(&hb);
    return (unsigned)ua | ((unsigned)ub << 16);
}

// ---------------------------------------------------------------------------
// prep1: per-batch prep. grid = B (8 blocks), block = 256 (thread = l).
//   mvm (masked values), bitsT (transposed mask bitmaps), tn, has, colmean,
//   cm, qt_out, pooled zero.
// ---------------------------------------------------------------------------
__global__ __launch_bounds__(256) void k_prep1(
    const float* __restrict__ values, const int* __restrict__ mask,
    const float* __restrict__ times,
    float* __restrict__ tn, float* __restrict__ has,
    float* __restrict__ cm, float* __restrict__ colmean,
    float* __restrict__ mvm, unsigned* __restrict__ bitsT,
    float* __restrict__ qt_out, float* __restrict__ pooled)
{
    __shared__ float val_s[256][33];     // raw values (for colmean), padded
    __shared__ unsigned bits_s[256];     // [d][w] = [32][8]
    __shared__ float partial_s[8][32];
    __shared__ float sminw[4], smaxw[4];
    __shared__ float sh[2];

    int b = blockIdx.x;
    int t = threadIdx.x;                 // = l

    const int*   mrow = mask   + (size_t)(b * L_ + t) * D_;
    const float* vrow = values + (size_t)(b * L_ + t) * D_;
    int4  m4[8];
    float4 v4[8];
    int any = 0;
    #pragma unroll
    for (int j = 0; j < 8; ++j) {
        m4[j] = reinterpret_cast<const int4*>(mrow)[j];
        v4[j] = reinterpret_cast<const float4*>(vrow)[j];
        any |= m4[j].x | m4[j].y | m4[j].z | m4[j].w;
        float4 mv;
        mv.x = m4[j].x ? v4[j].x : 0.f;
        mv.y = m4[j].y ? v4[j].y : 0.f;
        mv.z = m4[j].z ? v4[j].z : 0.f;
        mv.w = m4[j].w ? v4[j].w : 0.f;
        reinterpret_cast<float4*>(mvm + (size_t)(b * L_ + t) * D_)[j] = mv;
        val_s[t][j * 4 + 0] = v4[j].x;
        val_s[t][j * 4 + 1] = v4[j].y;
        val_s[t][j * 4 + 2] = v4[j].z;
        val_s[t][j * 4 + 3] = v4[j].w;
    }
    // transposed mask bitmaps: bitsT[b][d][w], bit (l&63) of wave ballot
    int wave = t >> 6;
    #pragma unroll
    for (int d = 0; d < D_; ++d) {
        int comp;
        { int j = d >> 2, c = d & 3;
          int4 mm = m4[j];
          comp = (c == 0) ? mm.x : (c == 1) ? mm.y : (c == 2) ? mm.z : mm.w; }
        unsigned long long bal = __ballot(comp != 0);
        if ((t & 63) == 0) {
            bits_s[d * 8 + wave * 2 + 0] = (unsigned)(bal & 0xffffffffull);
            bits_s[d * 8 + wave * 2 + 1] = (unsigned)(bal >> 32);
        }
    }
    // time min/max over observed steps: wave shfl reduce + tiny combine
    float tv = times[b * L_ + t];
    {
        float wmin = any ? tv : 1e38f;
        float wmax = any ? tv : -1e38f;
        #pragma unroll
        for (int off = 32; off > 0; off >>= 1) {
            wmin = fminf(wmin, __shfl_xor(wmin, off));
            wmax = fmaxf(wmax, __shfl_xor(wmax, off));
        }
        if ((t & 63) == 0) { sminw[wave] = wmin; smaxw[wave] = wmax; }
    }
    // colmean partials (independent of min/max)
    {
        int d = t & 31, lg = t >> 5;
        float ps = 0.f;
        #pragma unroll
        for (int i = 0; i < 32; ++i) ps += val_s[lg * 32 + i][d];
        partial_s[lg][d] = ps;
    }
    __syncthreads();
    if (t == 0) {
        float mn = fminf(fminf(sminw[0], sminw[1]), fminf(sminw[2], sminw[3]));
        float mx = fmaxf(fmaxf(smaxw[0], smaxw[1]), fmaxf(smaxw[2], smaxw[3]));
        float hv = (mn < 1e37f) ? 1.f : 0.f;
        sh[0] = (hv > 0.f) ? mn : 0.f;
        sh[1] = (hv > 0.f) ? mx : 1.f;
        has[b] = hv;
    }
    __syncthreads();
    float inv = 1.f / fmaxf(sh[1] - sh[0], 1e-6f);
    tn[b * L_ + t] = any ? (tv - sh[0]) * inv : 0.f;

    if (t < Q_) qt_out[b * Q_ + t] = (float)t * (1.f / 127.f);
    pooled[b * HID_ + t] = 0.f;                 // zero for k_main atomics
    bitsT[b * 256 + t] = bits_s[t];

    if (t < D_) {
        float s = 0.f;
        #pragma unroll
        for (int lg = 0; lg < 8; ++lg) s += partial_s[lg][t];
        colmean[b * D_ + t] = s * (1.f / (float)L_);
        unsigned o = 0;
        #pragma unroll
        for (int w = 0; w < 8; ++w) o |= bits_s[t * 8 + w];
        cm[b * D_ + t] = o ? 1.f : 0.f;
    }
}

// ---------------------------------------------------------------------------
// prep2: blocks 0..63: qproj (2 q/block). 64..319: kproj (8 rows/block).
//        320..351: wotvh bf16-pack transpose (4 c2/block).
//        352..359: cvec per batch.
// block = 256 threads
// ---------------------------------------------------------------------------
__global__ __launch_bounds__(256) void k_prep2(
    const float* __restrict__ tn, const float* __restrict__ cm,
    const float* __restrict__ w_per, const float* __restrict__ b_per,
    const float* __restrict__ w_lin, const float* __restrict__ b_lin,
    const float* __restrict__ wq, const float* __restrict__ bq,
    const float* __restrict__ wk, const float* __restrict__ bk,
    const float* __restrict__ wo, const float* __restrict__ bo,
    float* __restrict__ qproj, float* __restrict__ kproj,
    unsigned* __restrict__ wotvh, float* __restrict__ cvec)
{
    __shared__ __align__(16) float emb_q[2][E_];
    __shared__ __align__(16) float emb_k[8][E_];
    __shared__ float tsh[8];
    __shared__ float cm_s[D_];

    int blk = blockIdx.x;
    int t = threadIdx.x;

    if (blk < 64) {
        // q-projection: 2 q per block
        int half = t >> 7, e = t & 127;
        int q = blk * 2 + half;
        float tt = (float)q * (1.f / 127.f);
        emb_q[half][e] = (e == 0) ? (tt * w_lin[0] + b_lin[0])
                                  : __sinf(tt * w_per[e - 1] + b_per[e - 1]);
        __syncthreads();
        const float4* wr4 = reinterpret_cast<const float4*>(wq + (size_t)e * E_);
        const float4* e4  = reinterpret_cast<const float4*>(emb_q[half]);
        float acc = bq[e];
        #pragma unroll 8
        for (int j = 0; j < E_ / 4; ++j) {
            float4 w = wr4[j], x = e4[j];
            acc += w.x * x.x + w.y * x.y + w.z * x.z + w.w * x.w;
        }
        qproj[q * E_ + e] = acc;
    } else if (blk < 320) {
        // k-projection: 8 rows per block, 4 rows per thread-half
        int bl0 = (blk - 64) * 8;
        int e = t & 127, rh = t >> 7;
        if (t < 8) tsh[t] = tn[bl0 + t];
        __syncthreads();
        float wp = (e == 0) ? 0.f : w_per[e - 1];
        float bp = (e == 0) ? 0.f : b_per[e - 1];
        float wl = w_lin[0], bl = b_lin[0];
        #pragma unroll
        for (int rr = 0; rr < 4; ++rr) {
            int r = rh * 4 + rr;
            float tt = tsh[r];
            emb_k[r][e] = (e == 0) ? (tt * wl + bl) : __sinf(tt * wp + bp);
        }
        __syncthreads();
        const float4* wr4 = reinterpret_cast<const float4*>(wk + (size_t)e * E_);
        float bias = bk[e];
        float acc[4] = {bias, bias, bias, bias};
        #pragma unroll 8
        for (int j = 0; j < E_ / 4; ++j) {
            float4 w = wr4[j];
            #pragma unroll
            for (int rr = 0; rr < 4; ++rr) {
                float4 x = *reinterpret_cast<const float4*>(&emb_k[rh * 4 + rr][j * 4]);
                acc[rr] += w.x * x.x + w.y * x.y + w.z * x.z + w.w * x.w;
            }
        }
        #pragma unroll
        for (int rr = 0; rr < 4; ++rr)
            kproj[(size_t)(bl0 + rh * 4 + rr) * E_ + e] = acc[rr];
    } else if (blk < 352) {
        // wotvh: packed bf16 pairs of value-channel columns.
        // c2 pairs channels (2c2, 2c2+1); col(c) = (c>>5)*64 + (c&31)
        int c20 = (blk - 320) * 4;
        #pragma unroll
        for (int j = 0; j < 4; ++j) {
            int c2 = c20 + j;
            int ca = 2 * c2, cb = 2 * c2 + 1;
            int cola = (ca >> 5) * 64 + (ca & 31);
            int colb = (cb >> 5) * 64 + (cb & 31);
            float a = wo[(size_t)t * 512 + cola];
            float b = wo[(size_t)t * 512 + colb];
            wotvh[(size_t)c2 * HID_ + t] = pack_bf2(a, b);
        }
    } else {
        // cvec[b][hid] = bo[hid] + sum_r cm[b][r] * wo[hid][h1*64+32+r]
        int b = blk - 352;
        if (t < D_) cm_s[t] = cm[b * D_ + t];
        __syncthreads();
        int hid = t;
        const float4* wrow4 = reinterpret_cast<const float4*>(wo + (size_t)hid * 512);
        float accm = 0.f;
        #pragma unroll
        for (int h1 = 0; h1 < 8; ++h1) {
            #pragma unroll
            for (int j = 0; j < 8; ++j) {
                float4 w = wrow4[h1 * 16 + 8 + j];
                accm += cm_s[j * 4 + 0] * w.x + cm_s[j * 4 + 1] * w.y
                      + cm_s[j * 4 + 2] * w.z + cm_s[j * 4 + 3] * w.w;
            }
        }
        cvec[b * HID_ + hid] = bo[hid] + accm;
    }
}

// ---------------------------------------------------------------------------
// k_main: ONE q per block, grid (Q,B) = 1024 blocks (4 resident/CU), lean
//   LDS (~10.6 KB): no mvm staging (L2 reads), partials alias e_s.
//   Phase 1 (thread=l): s[h] from kproj row; per-head global max; e=exp(s-G).
//   Phase 2 (thread=(lseg,h,d4)): float4 accumulation over 64 l's of 4 d's,
//            mvm read from global (coalesced per-row), bits in registers.
//   Combine -> ctx_s[256]. GEMM vs bf16-packed wotvh + cvec. LN + pool.
// ---------------------------------------------------------------------------
__global__ __launch_bounds__(256, 4) void k_main(
    const float* __restrict__ qproj, const float* __restrict__ kproj,
    const float* __restrict__ mvm, const unsigned* __restrict__ bitsT,
    const float* __restrict__ cm, const float* __restrict__ colmean,
    const unsigned* __restrict__ wotvh, const float* __restrict__ cvec,
    const float* __restrict__ has,
    const float* __restrict__ ln_g, const float* __restrict__ ln_b,
    float* __restrict__ seq_out, float* __restrict__ pooled)
{
    int q = blockIdx.x, b = blockIdx.y;
    int tid = threadIdx.x;
    __shared__ __align__(16) float e_s[L_ * H_];   // 8 KB; aliased for partials
    __shared__ __align__(16) float qv_s[E_];
    __shared__ unsigned bits_s[256];
    __shared__ float gmax_s[H_];
    __shared__ __align__(8) float ctx_s[256];
    __shared__ float red_s[8];
    __shared__ float mu_rs[2];

    bits_s[tid] = bitsT[b * 256 + tid];
    if (tid < E_) qv_s[tid] = qproj[q * E_ + tid];
    __syncthreads();

    // Phase 1: scores (thread = l), raw s l-major in e_s
    const float4* kr4 = reinterpret_cast<const float4*>(kproj + (size_t)(b * L_ + tid) * E_);
    const float4* qv4 = reinterpret_cast<const float4*>(qv_s);
    float s[H_];
    #pragma unroll
    for (int h = 0; h < H_; ++h) {
        float acc = 0.f;
        #pragma unroll
        for (int j = 0; j < 4; ++j) {
            float4 kk = kr4[h * 4 + j], qq = qv4[h * 4 + j];
            acc += kk.x * qq.x + kk.y * qq.y + kk.z * qq.z + kk.w * qq.w;
        }
        s[h] = acc * 0.25f;                // 1/sqrt(EK=16)
    }
    {
        float4* er4 = reinterpret_cast<float4*>(&e_s[tid * 8]);
        er4[0] = *reinterpret_cast<float4*>(&s[0]);
        er4[1] = *reinterpret_cast<float4*>(&s[4]);
    }
    __syncthreads();
    // per-head global max (8 groups of 32 lanes)
    {
        int h = tid >> 5, ln = tid & 31;
        float mx = -1e30f;
        #pragma unroll
        for (int j = 0; j < 8; ++j) mx = fmaxf(mx, e_s[(ln + j * 32) * 8 + h]);
        #pragma unroll
        for (int off = 16; off > 0; off >>= 1) mx = fmaxf(mx, __shfl_xor(mx, off));
        if (ln == 0) gmax_s[h] = mx;
    }
    __syncthreads();
    {
        float e8[H_];
        #pragma unroll
        for (int h = 0; h < H_; ++h) e8[h] = __expf(s[h] - gmax_s[h]);
        float4* er4 = reinterpret_cast<float4*>(&e_s[tid * 8]);
        er4[0] = *reinterpret_cast<float4*>(&e8[0]);
        er4[1] = *reinterpret_cast<float4*>(&e8[4]);
    }
    __syncthreads();

    // Phase 2: thread = (lseg, h, d4); 64 l's x 4 d's; mvm from global (L2)
    {
        int lseg = tid >> 6, h = (tid >> 3) & 7, d4 = tid & 7;
        unsigned w0[4], w1[4];
        #pragma unroll
        for (int j = 0; j < 4; ++j) {
            int d = d4 * 4 + j;
            w0[j] = bits_s[d * 8 + lseg * 2 + 0];
            w1[j] = bits_s[d * 8 + lseg * 2 + 1];
        }
        float4 av  = {0.f, 0.f, 0.f, 0.f};
        float4 den = {0.f, 0.f, 0.f, 0.f};
        const float4* mvg = reinterpret_cast<const float4*>(mvm + (size_t)b * L_ * D_);
        int l0 = lseg * 64;
        #pragma unroll 8
        for (int i = 0; i < 32; ++i) {
            int l = l0 + i;
            float e = e_s[l * 8 + h];
            float4 m = mvg[l * 8 + d4];
            av.x += e * m.x; av.y += e * m.y; av.z += e * m.z; av.w += e * m.w;
            den.x += ((w0[0] >> i) & 1u) ? e : 0.f;
            den.y += ((w0[1] >> i) & 1u) ? e : 0.f;
            den.z += ((w0[2] >> i) & 1u) ? e : 0.f;
            den.w += ((w0[3] >> i) & 1u) ? e : 0.f;
        }
        #pragma unroll 8
        for (int i = 0; i < 32; ++i) {
            int l = l0 + 32 + i;
            float e = e_s[l * 8 + h];
            float4 m = mvg[l * 8 + d4];
            av.x += e * m.x; av.y += e * m.y; av.z += e * m.z; av.w += e * m.w;
            den.x += ((w1[0] >> i) & 1u) ? e : 0.f;
            den.y += ((w1[1] >> i) & 1u) ? e : 0.f;
            den.z += ((w1[2] >> i) & 1u) ? e : 0.f;
            den.w += ((w1[3] >> i) & 1u) ? e : 0.f;
        }
        __syncthreads();                 // all e_s reads complete
        float4* p4 = reinterpret_cast<float4*>(e_s);   // alias: partials
        p4[tid * 2 + 0] = av;
        p4[tid * 2 + 1] = den;
    }
    __syncthreads();
    // combine: thread tid = (hh, dd) writes ctx_s[tid]
    {
        int hh = tid >> 5, dd = tid & 31, dg = dd >> 2, jj = dd & 3;
        float a = 0.f, dn = 0.f;
        #pragma unroll
        for (int ls = 0; ls < 4; ++ls) {
            int pt = ls * 64 + hh * 8 + dg;
            a  += e_s[pt * 8 + jj];
            dn += e_s[pt * 8 + 4 + jj];
        }
        float cmf = cm[b * D_ + dd];
        ctx_s[tid] = (cmf > 0.f) ? (a / dn) : colmean[b * D_ + dd];
    }
    __syncthreads();

    // GEMM: thread = hid; K = 256 value channels via bf16-packed wotvh
    int hid = tid;
    float acc = cvec[b * HID_ + hid];
    #pragma unroll 8
    for (int c2 = 0; c2 < 128; ++c2) {
        unsigned u = wotvh[(size_t)c2 * HID_ + hid];
        float2 cc = *reinterpret_cast<const float2*>(&ctx_s[c2 * 2]);
        float w0 = __uint_as_float(u << 16);          // bf16 -> f32 exact
        float w1 = __uint_as_float(u & 0xffff0000u);
        acc += cc.x * w0 + cc.y * w1;
    }

    // fused LayerNorm (single row)
    int wave = hid >> 6;
    {
        float sum = acc, ssum = acc * acc;
        #pragma unroll
        for (int off = 32; off > 0; off >>= 1) {
            sum  += __shfl_xor(sum, off);
            ssum += __shfl_xor(ssum, off);
        }
        if ((hid & 63) == 0) { red_s[wave] = sum; red_s[4 + wave] = ssum; }
    }
    __syncthreads();
    if (hid == 0) {
        float S  = red_s[0] + red_s[1] + red_s[2] + red_s[3];
        float SS = red_s[4] + red_s[5] + red_s[6] + red_s[7];
        float mu = S * (1.f / HID_);
        float var = SS * (1.f / HID_) - mu * mu;
        mu_rs[0] = mu;
        mu_rs[1] = rsqrtf(var + 1e-5f);
    }
    __syncthreads();

    float outv = ((acc - mu_rs[0]) * mu_rs[1] * ln_g[hid] + ln_b[hid]) * has[b];
    seq_out[((size_t)(b * Q_ + q)) * HID_ + hid] = outv;
    atomicAdd(&pooled[b * HID_ + hid], outv * (1.f / (float)Q_));
}

// ---------------------------------------------------------------------------
extern "C" void kernel_launch(void* const* d_in, const int* in_sizes, int n_in,
                              void* d_out, int out_size, void* d_ws, size_t ws_size,
                              hipStream_t stream)
{
    const float* values = (const float*)d_in[0];
    const int*   mask   = (const int*)  d_in[1];
    const float* times  = (const float*)d_in[2];
    const float* w_per  = (const float*)d_in[3];
    const float* b_per  = (const float*)d_in[4];
    const float* w_lin  = (const float*)d_in[5];
    const float* b_lin  = (const float*)d_in[6];
    const float* wq     = (const float*)d_in[7];
    const float* bq     = (const float*)d_in[8];
    const float* wk     = (const float*)d_in[9];
    const float* bk     = (const float*)d_in[10];
    const float* wo     = (const float*)d_in[11];
    const float* bo     = (const float*)d_in[12];
    const float* ln_g   = (const float*)d_in[13];
    const float* ln_b   = (const float*)d_in[14];

    float* out     = (float*)d_out;
    float* seq_out = out;                        // B*Q*HID = 262144
    float* pooled  = out + 262144;               // B*HID   = 2048
    float* qt_out  = out + 262144 + 2048;        // B*Q     = 1024

    float* ws         = (float*)d_ws;
    float*    tn      = ws;                      // 2048
    float*    has     = ws + 2048;               // 8
    float*    cm      = ws + 2056;               // 256
    float*    colmean = ws + 2312;               // 256
    float*    qproj   = ws + 2568;               // 16384  (byte 10272, 16B-aligned)
    unsigned* bitsT   = (unsigned*)(ws + 18952); // 2048 u32
    float*    mvm     = ws + 21000;              // 65536  (byte 84000, 16B-aligned)
    float*    kproj   = ws + 86536;              // 262144 (byte 346144, 16B-aligned)
    float*    cvec    = ws + 348680;             // 2048
    unsigned* wotvh   = (unsigned*)(ws + 350728); // 32768 u32 -> end 1.53 MB

    k_prep1<<<B_,           256, 0, stream>>>(values, mask, times,
                 tn, has, cm, colmean, mvm, bitsT, qt_out, pooled);
    k_prep2<<<360,          256, 0, stream>>>(tn, cm, w_per, b_per, w_lin, b_lin,
                 wq, bq, wk, bk, wo, bo, qproj, kproj, wotvh, cvec);
    k_main <<<dim3(Q_, B_), 256, 0, stream>>>(qproj, kproj, mvm, bitsT,
                 cm, colmean, wotvh, cvec, has, ln_g, ln_b, seq_out, pooled);
}

// Round 12
// 137.759 us; speedup vs baseline: 1.0463x; 1.0463x over previous
//
#include <hip/hip_runtime.h>
#include <hip/hip_bf16.h>

// Dims (fixed by the problem)
#define B_   8
#define L_   256
#define D_   32
#define E_   128
#define H_   8
#define Q_   128
#define HID_ 256

__device__ __forceinline__ unsigned pack_bf2(float a, float b)
{
    __hip_bfloat16 ha = __float2bfloat16(a);
    __hip_bfloat16 hb = __float2bfloat16(b);
    unsigned short ua = *reinterpret_cast<unsigned short*>(&ha);
    unsigned short ub = *reinterpret_cast<unsigned short*>(&hb);
    return (unsigned)ua | ((unsigned)ub << 16);
}

// ---------------------------------------------------------------------------
// prep1: per-batch prep. grid = B (8 blocks), block = 256 (thread = l).
//   mvm (masked values), bitsT (transposed mask bitmaps), tn, has, colmean,
//   cm, qt_out, pooled zero.
// ---------------------------------------------------------------------------
__global__ __launch_bounds__(256) void k_prep1(
    const float* __restrict__ values, const int* __restrict__ mask,
    const float* __restrict__ times,
    float* __restrict__ tn, float* __restrict__ has,
    float* __restrict__ cm, float* __restrict__ colmean,
    float* __restrict__ mvm, unsigned* __restrict__ bitsT,
    float* __restrict__ qt_out, float* __restrict__ pooled)
{
    __shared__ float val_s[256][33];     // raw values (for colmean), padded
    __shared__ unsigned bits_s[256];     // [d][w] = [32][8]
    __shared__ float partial_s[8][32];
    __shared__ float sminw[4], smaxw[4];
    __shared__ float sh[2];

    int b = blockIdx.x;
    int t = threadIdx.x;                 // = l

    const int*   mrow = mask   + (size_t)(b * L_ + t) * D_;
    const float* vrow = values + (size_t)(b * L_ + t) * D_;
    int4  m4[8];
    float4 v4[8];
    int any = 0;
    #pragma unroll
    for (int j = 0; j < 8; ++j) {
        m4[j] = reinterpret_cast<const int4*>(mrow)[j];
        v4[j] = reinterpret_cast<const float4*>(vrow)[j];
        any |= m4[j].x | m4[j].y | m4[j].z | m4[j].w;
        float4 mv;
        mv.x = m4[j].x ? v4[j].x : 0.f;
        mv.y = m4[j].y ? v4[j].y : 0.f;
        mv.z = m4[j].z ? v4[j].z : 0.f;
        mv.w = m4[j].w ? v4[j].w : 0.f;
        reinterpret_cast<float4*>(mvm + (size_t)(b * L_ + t) * D_)[j] = mv;
        val_s[t][j * 4 + 0] = v4[j].x;
        val_s[t][j * 4 + 1] = v4[j].y;
        val_s[t][j * 4 + 2] = v4[j].z;
        val_s[t][j * 4 + 3] = v4[j].w;
    }
    // transposed mask bitmaps: bitsT[b][d][w], bit (l&63) of wave ballot
    int wave = t >> 6;
    #pragma unroll
    for (int d = 0; d < D_; ++d) {
        int comp;
        { int j = d >> 2, c = d & 3;
          int4 mm = m4[j];
          comp = (c == 0) ? mm.x : (c == 1) ? mm.y : (c == 2) ? mm.z : mm.w; }
        unsigned long long bal = __ballot(comp != 0);
        if ((t & 63) == 0) {
            bits_s[d * 8 + wave * 2 + 0] = (unsigned)(bal & 0xffffffffull);
            bits_s[d * 8 + wave * 2 + 1] = (unsigned)(bal >> 32);
        }
    }
    // time min/max over observed steps: wave shfl reduce + tiny combine
    float tv = times[b * L_ + t];
    {
        float wmin = any ? tv : 1e38f;
        float wmax = any ? tv : -1e38f;
        #pragma unroll
        for (int off = 32; off > 0; off >>= 1) {
            wmin = fminf(wmin, __shfl_xor(wmin, off));
            wmax = fmaxf(wmax, __shfl_xor(wmax, off));
        }
        if ((t & 63) == 0) { sminw[wave] = wmin; smaxw[wave] = wmax; }
    }
    // colmean partials (independent of min/max)
    {
        int d = t & 31, lg = t >> 5;
        float ps = 0.f;
        #pragma unroll
        for (int i = 0; i < 32; ++i) ps += val_s[lg * 32 + i][d];
        partial_s[lg][d] = ps;
    }
    __syncthreads();
    if (t == 0) {
        float mn = fminf(fminf(sminw[0], sminw[1]), fminf(sminw[2], sminw[3]));
        float mx = fmaxf(fmaxf(smaxw[0], smaxw[1]), fmaxf(smaxw[2], smaxw[3]));
        float hv = (mn < 1e37f) ? 1.f : 0.f;
        sh[0] = (hv > 0.f) ? mn : 0.f;
        sh[1] = (hv > 0.f) ? mx : 1.f;
        has[b] = hv;
    }
    __syncthreads();
    float inv = 1.f / fmaxf(sh[1] - sh[0], 1e-6f);
    tn[b * L_ + t] = any ? (tv - sh[0]) * inv : 0.f;

    if (t < Q_) qt_out[b * Q_ + t] = (float)t * (1.f / 127.f);
    pooled[b * HID_ + t] = 0.f;                 // zero for k_main atomics
    bitsT[b * 256 + t] = bits_s[t];

    if (t < D_) {
        float s = 0.f;
        #pragma unroll
        for (int lg = 0; lg < 8; ++lg) s += partial_s[lg][t];
        colmean[b * D_ + t] = s * (1.f / (float)L_);
        unsigned o = 0;
        #pragma unroll
        for (int w = 0; w < 8; ++w) o |= bits_s[t * 8 + w];
        cm[b * D_ + t] = o ? 1.f : 0.f;
    }
}

// ---------------------------------------------------------------------------
// prep2: blocks 0..63: qproj (2 q/block). 64..319: kproj (8 rows/block).
//        320..351: wotvh bf16-pack transpose (4 c2/block).
//        352..359: cvec per batch.
// block = 256 threads
// ---------------------------------------------------------------------------
__global__ __launch_bounds__(256) void k_prep2(
    const float* __restrict__ tn, const float* __restrict__ cm,
    const float* __restrict__ w_per, const float* __restrict__ b_per,
    const float* __restrict__ w_lin, const float* __restrict__ b_lin,
    const float* __restrict__ wq, const float* __restrict__ bq,
    const float* __restrict__ wk, const float* __restrict__ bk,
    const float* __restrict__ wo, const float* __restrict__ bo,
    float* __restrict__ qproj, float* __restrict__ kproj,
    unsigned* __restrict__ wotvh, float* __restrict__ cvec)
{
    __shared__ __align__(16) float emb_q[2][E_];
    __shared__ __align__(16) float emb_k[8][E_];
    __shared__ float tsh[8];
    __shared__ float cm_s[D_];

    int blk = blockIdx.x;
    int t = threadIdx.x;

    if (blk < 64) {
        // q-projection: 2 q per block
        int half = t >> 7, e = t & 127;
        int q = blk * 2 + half;
        float tt = (float)q * (1.f / 127.f);
        emb_q[half][e] = (e == 0) ? (tt * w_lin[0] + b_lin[0])
                                  : __sinf(tt * w_per[e - 1] + b_per[e - 1]);
        __syncthreads();
        const float4* wr4 = reinterpret_cast<const float4*>(wq + (size_t)e * E_);
        const float4* e4  = reinterpret_cast<const float4*>(emb_q[half]);
        float acc = bq[e];
        #pragma unroll 8
        for (int j = 0; j < E_ / 4; ++j) {
            float4 w = wr4[j], x = e4[j];
            acc += w.x * x.x + w.y * x.y + w.z * x.z + w.w * x.w;
        }
        qproj[q * E_ + e] = acc;
    } else if (blk < 320) {
        // k-projection: 8 rows per block, 4 rows per thread-half
        int bl0 = (blk - 64) * 8;
        int e = t & 127, rh = t >> 7;
        if (t < 8) tsh[t] = tn[bl0 + t];
        __syncthreads();
        float wp = (e == 0) ? 0.f : w_per[e - 1];
        float bp = (e == 0) ? 0.f : b_per[e - 1];
        float wl = w_lin[0], bl = b_lin[0];
        #pragma unroll
        for (int rr = 0; rr < 4; ++rr) {
            int r = rh * 4 + rr;
            float tt = tsh[r];
            emb_k[r][e] = (e == 0) ? (tt * wl + bl) : __sinf(tt * wp + bp);
        }
        __syncthreads();
        const float4* wr4 = reinterpret_cast<const float4*>(wk + (size_t)e * E_);
        float bias = bk[e];
        float acc[4] = {bias, bias, bias, bias};
        #pragma unroll 8
        for (int j = 0; j < E_ / 4; ++j) {
            float4 w = wr4[j];
            #pragma unroll
            for (int rr = 0; rr < 4; ++rr) {
                float4 x = *reinterpret_cast<const float4*>(&emb_k[rh * 4 + rr][j * 4]);
                acc[rr] += w.x * x.x + w.y * x.y + w.z * x.z + w.w * x.w;
            }
        }
        #pragma unroll
        for (int rr = 0; rr < 4; ++rr)
            kproj[(size_t)(bl0 + rh * 4 + rr) * E_ + e] = acc[rr];
    } else if (blk < 352) {
        // wotvh: packed bf16 pairs of value-channel columns.
        // c2 pairs channels (2c2, 2c2+1); col(c) = (c>>5)*64 + (c&31)
        int c20 = (blk - 320) * 4;
        #pragma unroll
        for (int j = 0; j < 4; ++j) {
            int c2 = c20 + j;
            int ca = 2 * c2, cb = 2 * c2 + 1;
            int cola = (ca >> 5) * 64 + (ca & 31);
            int colb = (cb >> 5) * 64 + (cb & 31);
            float a = wo[(size_t)t * 512 + cola];
            float b = wo[(size_t)t * 512 + colb];
            wotvh[(size_t)c2 * HID_ + t] = pack_bf2(a, b);
        }
    } else {
        // cvec[b][hid] = bo[hid] + sum_r cm[b][r] * wo[hid][h1*64+32+r]
        int b = blk - 352;
        if (t < D_) cm_s[t] = cm[b * D_ + t];
        __syncthreads();
        int hid = t;
        const float4* wrow4 = reinterpret_cast<const float4*>(wo + (size_t)hid * 512);
        float accm = 0.f;
        #pragma unroll
        for (int h1 = 0; h1 < 8; ++h1) {
            #pragma unroll
            for (int j = 0; j < 8; ++j) {
                float4 w = wrow4[h1 * 16 + 8 + j];
                accm += cm_s[j * 4 + 0] * w.x + cm_s[j * 4 + 1] * w.y
                      + cm_s[j * 4 + 2] * w.z + cm_s[j * 4 + 3] * w.w;
            }
        }
        cvec[b * HID_ + hid] = bo[hid] + accm;
    }
}

// ---------------------------------------------------------------------------
// k_main: 512 threads, TWO q rows per block (thread = (qi, t)); grid
//   (Q/2, B) = 512 blocks, 2 blocks/CU = 16 waves/CU. Full LDS mvm staging
//   (amortized over 2 rows), per-thread work = 1 row.
//   Phase 1 (qi, l=t): s[h]; per-(qi,h) global max; e = exp(s - G).
//   Phase 2 (qi, lseg, h, d4): float4 accumulation, 64 l x 4 d; partials
//            alias e_s[qi]. Combine -> ctx_s[qi][256].
//   GEMM (qi, hid=t): bf16-packed wotvh + cvec. LN per row + pool.
// ---------------------------------------------------------------------------
__global__ __launch_bounds__(512, 4) void k_main(
    const float* __restrict__ qproj, const float* __restrict__ kproj,
    const float* __restrict__ mvm, const unsigned* __restrict__ bitsT,
    const float* __restrict__ cm, const float* __restrict__ colmean,
    const unsigned* __restrict__ wotvh, const float* __restrict__ cvec,
    const float* __restrict__ has,
    const float* __restrict__ ln_g, const float* __restrict__ ln_b,
    float* __restrict__ seq_out, float* __restrict__ pooled)
{
    int qb = blockIdx.x, b = blockIdx.y;
    int tid = threadIdx.x;               // 0..511
    int qi = tid >> 8, t = tid & 255;
    __shared__ __align__(16) float mvm_s[L_ * D_];    // 32 KB
    __shared__ __align__(16) float e_s[2][L_ * H_];   // 16 KB; aliased for partials
    __shared__ __align__(16) float qv_s[2][E_];
    __shared__ unsigned bits_s[256];
    __shared__ float gmax_s[16];
    __shared__ __align__(16) float ctx_s[2][256];
    __shared__ float red_s[2][8];
    __shared__ float mu_rs[2][2];

    // stage: mvm (coalesced float4 by all 512), bits, qv per half
    {
        const float4* src = reinterpret_cast<const float4*>(mvm + (size_t)b * L_ * D_);
        float4* dst = reinterpret_cast<float4*>(mvm_s);
        #pragma unroll
        for (int j = 0; j < 4; ++j) dst[tid + j * 512] = src[tid + j * 512];
        if (qi == 0) bits_s[t] = bitsT[b * 256 + t];
        if (t < E_) qv_s[qi][t] = qproj[(qb * 2 + qi) * E_ + t];
    }
    __syncthreads();

    // Phase 1: thread (qi, l=t): scores for row qi, raw s l-major
    const float4* kr4 = reinterpret_cast<const float4*>(kproj + (size_t)(b * L_ + t) * E_);
    const float4* qv4 = reinterpret_cast<const float4*>(qv_s[qi]);
    float s[H_];
    #pragma unroll
    for (int h = 0; h < H_; ++h) {
        float acc = 0.f;
        #pragma unroll
        for (int j = 0; j < 4; ++j) {
            float4 kk = kr4[h * 4 + j], qq = qv4[h * 4 + j];
            acc += kk.x * qq.x + kk.y * qq.y + kk.z * qq.z + kk.w * qq.w;
        }
        s[h] = acc * 0.25f;                // 1/sqrt(EK=16)
    }
    {
        float4* er4 = reinterpret_cast<float4*>(&e_s[qi][t * 8]);
        er4[0] = *reinterpret_cast<float4*>(&s[0]);
        er4[1] = *reinterpret_cast<float4*>(&s[4]);
    }
    __syncthreads();
    // per-(qi,h) global max: 16 groups of 32 lanes
    {
        int g = tid >> 5, ln = tid & 31;
        int gq = g >> 3, h = g & 7;
        float mx = -1e30f;
        #pragma unroll
        for (int j = 0; j < 8; ++j) mx = fmaxf(mx, e_s[gq][(ln + j * 32) * 8 + h]);
        #pragma unroll
        for (int off = 16; off > 0; off >>= 1) mx = fmaxf(mx, __shfl_xor(mx, off));
        if (ln == 0) gmax_s[g] = mx;
    }
    __syncthreads();
    {
        float e8[H_];
        #pragma unroll
        for (int h = 0; h < H_; ++h) e8[h] = __expf(s[h] - gmax_s[qi * 8 + h]);
        float4* er4 = reinterpret_cast<float4*>(&e_s[qi][t * 8]);
        er4[0] = *reinterpret_cast<float4*>(&e8[0]);
        er4[1] = *reinterpret_cast<float4*>(&e8[4]);
    }
    __syncthreads();

    // Phase 2: thread (qi, lseg=t>>6, h=(t>>3)&7, d4=t&7); 64 l x 4 d
    {
        int lseg = t >> 6, h = (t >> 3) & 7, d4 = t & 7;
        unsigned w0[4], w1[4];
        #pragma unroll
        for (int j = 0; j < 4; ++j) {
            int d = d4 * 4 + j;
            w0[j] = bits_s[d * 8 + lseg * 2 + 0];
            w1[j] = bits_s[d * 8 + lseg * 2 + 1];
        }
        float4 av  = {0.f, 0.f, 0.f, 0.f};
        float4 den = {0.f, 0.f, 0.f, 0.f};
        const float4* mv4 = reinterpret_cast<const float4*>(mvm_s);
        const float* ep = e_s[qi];
        int l0 = lseg * 64;
        #pragma unroll 8
        for (int i = 0; i < 32; ++i) {
            int l = l0 + i;
            float e = ep[l * 8 + h];
            float4 m = mv4[l * 8 + d4];
            av.x += e * m.x; av.y += e * m.y; av.z += e * m.z; av.w += e * m.w;
            den.x += ((w0[0] >> i) & 1u) ? e : 0.f;
            den.y += ((w0[1] >> i) & 1u) ? e : 0.f;
            den.z += ((w0[2] >> i) & 1u) ? e : 0.f;
            den.w += ((w0[3] >> i) & 1u) ? e : 0.f;
        }
        #pragma unroll 8
        for (int i = 0; i < 32; ++i) {
            int l = l0 + 32 + i;
            float e = ep[l * 8 + h];
            float4 m = mv4[l * 8 + d4];
            av.x += e * m.x; av.y += e * m.y; av.z += e * m.z; av.w += e * m.w;
            den.x += ((w1[0] >> i) & 1u) ? e : 0.f;
            den.y += ((w1[1] >> i) & 1u) ? e : 0.f;
            den.z += ((w1[2] >> i) & 1u) ? e : 0.f;
            den.w += ((w1[3] >> i) & 1u) ? e : 0.f;
        }
        __syncthreads();                 // all e_s reads complete
        float4* p4 = reinterpret_cast<float4*>(e_s[qi]);   // alias: partials (8 KB/row)
        p4[t * 2 + 0] = av;
        p4[t * 2 + 1] = den;
    }
    __syncthreads();
    // combine: thread (qi, hh=t>>5, dd=t&31) writes ctx_s[qi][t]
    {
        const float* part = e_s[qi];
        int hh = t >> 5, dd = t & 31, dg = dd >> 2, jj = dd & 3;
        float a = 0.f, dn = 0.f;
        #pragma unroll
        for (int ls = 0; ls < 4; ++ls) {
            int pt = ls * 64 + hh * 8 + dg;
            a  += part[pt * 8 + jj];
            dn += part[pt * 8 + 4 + jj];
        }
        float cmf = cm[b * D_ + dd];
        ctx_s[qi][t] = (cmf > 0.f) ? (a / dn) : colmean[b * D_ + dd];
    }
    __syncthreads();

    // GEMM: thread (qi, hid=t); K = 256 value channels via bf16-packed wotvh
    int hid = t;
    float acc = cvec[b * HID_ + hid];
    #pragma unroll 8
    for (int c2 = 0; c2 < 128; ++c2) {
        unsigned u = wotvh[(size_t)c2 * HID_ + hid];
        float2 cc = *reinterpret_cast<const float2*>(&ctx_s[qi][c2 * 2]);
        float w0 = __uint_as_float(u << 16);          // bf16 -> f32 exact
        float w1 = __uint_as_float(u & 0xffff0000u);
        acc += cc.x * w0 + cc.y * w1;
    }

    // fused LayerNorm per row (waves 0-3 = row0, 4-7 = row1)
    int wave = tid >> 6;
    {
        float sum = acc, ssum = acc * acc;
        #pragma unroll
        for (int off = 32; off > 0; off >>= 1) {
            sum  += __shfl_xor(sum, off);
            ssum += __shfl_xor(ssum, off);
        }
        if ((tid & 63) == 0) {
            red_s[qi][wave & 3]     = sum;
            red_s[qi][4 + (wave & 3)] = ssum;
        }
    }
    __syncthreads();
    if (t == 0) {                        // tid 0 and 256: one per row
        float S  = red_s[qi][0] + red_s[qi][1] + red_s[qi][2] + red_s[qi][3];
        float SS = red_s[qi][4] + red_s[qi][5] + red_s[qi][6] + red_s[qi][7];
        float mu = S * (1.f / HID_);
        float var = SS * (1.f / HID_) - mu * mu;
        mu_rs[qi][0] = mu;
        mu_rs[qi][1] = rsqrtf(var + 1e-5f);
    }
    __syncthreads();

    float outv = ((acc - mu_rs[qi][0]) * mu_rs[qi][1] * ln_g[hid] + ln_b[hid]) * has[b];
    seq_out[((size_t)(b * Q_ + qb * 2 + qi)) * HID_ + hid] = outv;
    atomicAdd(&pooled[b * HID_ + hid], outv * (1.f / (float)Q_));
}

// ---------------------------------------------------------------------------
extern "C" void kernel_launch(void* const* d_in, const int* in_sizes, int n_in,
                              void* d_out, int out_size, void* d_ws, size_t ws_size,
                              hipStream_t stream)
{
    const float* values = (const float*)d_in[0];
    const int*   mask   = (const int*)  d_in[1];
    const float* times  = (const float*)d_in[2];
    const float* w_per  = (const float*)d_in[3];
    const float* b_per  = (const float*)d_in[4];
    const float* w_lin  = (const float*)d_in[5];
    const float* b_lin  = (const float*)d_in[6];
    const float* wq     = (const float*)d_in[7];
    const float* bq     = (const float*)d_in[8];
    const float* wk     = (const float*)d_in[9];
    const float* bk     = (const float*)d_in[10];
    const float* wo     = (const float*)d_in[11];
    const float* bo     = (const float*)d_in[12];
    const float* ln_g   = (const float*)d_in[13];
    const float* ln_b   = (const float*)d_in[14];

    float* out     = (float*)d_out;
    float* seq_out = out;                        // B*Q*HID = 262144
    float* pooled  = out + 262144;               // B*HID   = 2048
    float* qt_out  = out + 262144 + 2048;        // B*Q     = 1024

    float* ws         = (float*)d_ws;
    float*    tn      = ws;                      // 2048
    float*    has     = ws + 2048;               // 8
    float*    cm      = ws + 2056;               // 256
    float*    colmean = ws + 2312;               // 256
    float*    qproj   = ws + 2568;               // 16384  (byte 10272, 16B-aligned)
    unsigned* bitsT   = (unsigned*)(ws + 18952); // 2048 u32
    float*    mvm     = ws + 21000;              // 65536  (byte 84000, 16B-aligned)
    float*    kproj   = ws + 86536;              // 262144 (byte 346144, 16B-aligned)
    float*    cvec    = ws + 348680;             // 2048
    unsigned* wotvh   = (unsigned*)(ws + 350728); // 32768 u32 -> end 1.53 MB

    k_prep1<<<B_,               256, 0, stream>>>(values, mask, times,
                 tn, has, cm, colmean, mvm, bitsT, qt_out, pooled);
    k_prep2<<<360,              256, 0, stream>>>(tn, cm, w_per, b_per, w_lin, b_lin,
                 wq, bq, wk, bk, wo, bo, qproj, kproj, wotvh, cvec);
    k_main <<<dim3(Q_ / 2, B_), 512, 0, stream>>>(qproj, kproj, mvm, bitsT,
                 cm, colmean, wotvh, cvec, has, ln_g, ln_b, seq_out, pooled);
}

// Round 13
// 129.785 us; speedup vs baseline: 1.1106x; 1.0614x over previous
//
#include <hip/hip_runtime.h>
#include <hip/hip_bf16.h>

// Dims (fixed by the problem)
#define B_   8
#define L_   256
#define D_   32
#define E_   128
#define H_   8
#define Q_   128
#define HID_ 256

__device__ __forceinline__ unsigned pack_bf2(float a, float b)
{
    __hip_bfloat16 ha = __float2bfloat16(a);
    __hip_bfloat16 hb = __float2bfloat16(b);
    unsigned short ua = *reinterpret_cast<unsigned short*>(&ha);
    unsigned short ub = *reinterpret_cast<unsigned short*>(&hb);
    return (unsigned)ua | ((unsigned)ub << 16);
}

// ---------------------------------------------------------------------------
// prep1: per-batch prep. grid = B (8 blocks), block = 256 (thread = l).
//   mvm (masked values), bitsT (transposed mask bitmaps), tn, has, colmean,
//   cm, qt_out, pooled zero.
// ---------------------------------------------------------------------------
__global__ __launch_bounds__(256) void k_prep1(
    const float* __restrict__ values, const int* __restrict__ mask,
    const float* __restrict__ times,
    float* __restrict__ tn, float* __restrict__ has,
    float* __restrict__ cm, float* __restrict__ colmean,
    float* __restrict__ mvm, unsigned* __restrict__ bitsT,
    float* __restrict__ qt_out, float* __restrict__ pooled)
{
    __shared__ float val_s[256][33];     // raw values (for colmean), padded
    __shared__ unsigned bits_s[256];     // [d][w] = [32][8]
    __shared__ float partial_s[8][32];
    __shared__ float sminw[4], smaxw[4];
    __shared__ float sh[2];

    int b = blockIdx.x;
    int t = threadIdx.x;                 // = l

    const int*   mrow = mask   + (size_t)(b * L_ + t) * D_;
    const float* vrow = values + (size_t)(b * L_ + t) * D_;
    int4  m4[8];
    float4 v4[8];
    int any = 0;
    #pragma unroll
    for (int j = 0; j < 8; ++j) {
        m4[j] = reinterpret_cast<const int4*>(mrow)[j];
        v4[j] = reinterpret_cast<const float4*>(vrow)[j];
        any |= m4[j].x | m4[j].y | m4[j].z | m4[j].w;
        float4 mv;
        mv.x = m4[j].x ? v4[j].x : 0.f;
        mv.y = m4[j].y ? v4[j].y : 0.f;
        mv.z = m4[j].z ? v4[j].z : 0.f;
        mv.w = m4[j].w ? v4[j].w : 0.f;
        reinterpret_cast<float4*>(mvm + (size_t)(b * L_ + t) * D_)[j] = mv;
        val_s[t][j * 4 + 0] = v4[j].x;
        val_s[t][j * 4 + 1] = v4[j].y;
        val_s[t][j * 4 + 2] = v4[j].z;
        val_s[t][j * 4 + 3] = v4[j].w;
    }
    // transposed mask bitmaps: bitsT[b][d][w], bit (l&63) of wave ballot
    int wave = t >> 6;
    #pragma unroll
    for (int d = 0; d < D_; ++d) {
        int comp;
        { int j = d >> 2, c = d & 3;
          int4 mm = m4[j];
          comp = (c == 0) ? mm.x : (c == 1) ? mm.y : (c == 2) ? mm.z : mm.w; }
        unsigned long long bal = __ballot(comp != 0);
        if ((t & 63) == 0) {
            bits_s[d * 8 + wave * 2 + 0] = (unsigned)(bal & 0xffffffffull);
            bits_s[d * 8 + wave * 2 + 1] = (unsigned)(bal >> 32);
        }
    }
    // time min/max over observed steps: wave shfl reduce + tiny combine
    float tv = times[b * L_ + t];
    {
        float wmin = any ? tv : 1e38f;
        float wmax = any ? tv : -1e38f;
        #pragma unroll
        for (int off = 32; off > 0; off >>= 1) {
            wmin = fminf(wmin, __shfl_xor(wmin, off));
            wmax = fmaxf(wmax, __shfl_xor(wmax, off));
        }
        if ((t & 63) == 0) { sminw[wave] = wmin; smaxw[wave] = wmax; }
    }
    // colmean partials (independent of min/max)
    {
        int d = t & 31, lg = t >> 5;
        float ps = 0.f;
        #pragma unroll
        for (int i = 0; i < 32; ++i) ps += val_s[lg * 32 + i][d];
        partial_s[lg][d] = ps;
    }
    __syncthreads();
    if (t == 0) {
        float mn = fminf(fminf(sminw[0], sminw[1]), fminf(sminw[2], sminw[3]));
        float mx = fmaxf(fmaxf(smaxw[0], smaxw[1]), fmaxf(smaxw[2], smaxw[3]));
        float hv = (mn < 1e37f) ? 1.f : 0.f;
        sh[0] = (hv > 0.f) ? mn : 0.f;
        sh[1] = (hv > 0.f) ? mx : 1.f;
        has[b] = hv;
    }
    __syncthreads();
    float inv = 1.f / fmaxf(sh[1] - sh[0], 1e-6f);
    tn[b * L_ + t] = any ? (tv - sh[0]) * inv : 0.f;

    if (t < Q_) qt_out[b * Q_ + t] = (float)t * (1.f / 127.f);
    pooled[b * HID_ + t] = 0.f;                 // zero for k_main atomics
    bitsT[b * 256 + t] = bits_s[t];

    if (t < D_) {
        float s = 0.f;
        #pragma unroll
        for (int lg = 0; lg < 8; ++lg) s += partial_s[lg][t];
        colmean[b * D_ + t] = s * (1.f / (float)L_);
        unsigned o = 0;
        #pragma unroll
        for (int w = 0; w < 8; ++w) o |= bits_s[t * 8 + w];
        cm[b * D_ + t] = o ? 1.f : 0.f;
    }
}

// ---------------------------------------------------------------------------
// prep2: blocks 0..63: qproj (2 q/block). 64..319: kproj -> TRANSPOSED
//        kprojT[b][e][l] (8 rows/block). 320..351: wotvh bf16-pack transpose.
//        352..359: cvec per batch.
// block = 256 threads
// ---------------------------------------------------------------------------
__global__ __launch_bounds__(256) void k_prep2(
    const float* __restrict__ tn, const float* __restrict__ cm,
    const float* __restrict__ w_per, const float* __restrict__ b_per,
    const float* __restrict__ w_lin, const float* __restrict__ b_lin,
    const float* __restrict__ wq, const float* __restrict__ bq,
    const float* __restrict__ wk, const float* __restrict__ bk,
    const float* __restrict__ wo, const float* __restrict__ bo,
    float* __restrict__ qproj, float* __restrict__ kprojT,
    unsigned* __restrict__ wotvh, float* __restrict__ cvec)
{
    __shared__ __align__(16) float emb_q[2][E_];
    __shared__ __align__(16) float emb_k[8][E_];
    __shared__ float tsh[8];
    __shared__ float cm_s[D_];

    int blk = blockIdx.x;
    int t = threadIdx.x;

    if (blk < 64) {
        // q-projection: 2 q per block
        int half = t >> 7, e = t & 127;
        int q = blk * 2 + half;
        float tt = (float)q * (1.f / 127.f);
        emb_q[half][e] = (e == 0) ? (tt * w_lin[0] + b_lin[0])
                                  : __sinf(tt * w_per[e - 1] + b_per[e - 1]);
        __syncthreads();
        const float4* wr4 = reinterpret_cast<const float4*>(wq + (size_t)e * E_);
        const float4* e4  = reinterpret_cast<const float4*>(emb_q[half]);
        float acc = bq[e];
        #pragma unroll 8
        for (int j = 0; j < E_ / 4; ++j) {
            float4 w = wr4[j], x = e4[j];
            acc += w.x * x.x + w.y * x.y + w.z * x.z + w.w * x.w;
        }
        qproj[q * E_ + e] = acc;
    } else if (blk < 320) {
        // k-projection: 8 rows per block, 4 rows per thread-half;
        // OUTPUT TRANSPOSED: kprojT[(b*E + e)*L + l]
        int r0 = (blk - 64) * 8;         // global row = b*L + l0
        int b = r0 >> 8, l0 = r0 & 255;
        int e = t & 127, rh = t >> 7;
        if (t < 8) tsh[t] = tn[r0 + t];
        __syncthreads();
        float wp = (e == 0) ? 0.f : w_per[e - 1];
        float bp = (e == 0) ? 0.f : b_per[e - 1];
        float wl = w_lin[0], bl = b_lin[0];
        #pragma unroll
        for (int rr = 0; rr < 4; ++rr) {
            int r = rh * 4 + rr;
            float tt = tsh[r];
            emb_k[r][e] = (e == 0) ? (tt * wl + bl) : __sinf(tt * wp + bp);
        }
        __syncthreads();
        const float4* wr4 = reinterpret_cast<const float4*>(wk + (size_t)e * E_);
        float bias = bk[e];
        float acc[4] = {bias, bias, bias, bias};
        #pragma unroll 8
        for (int j = 0; j < E_ / 4; ++j) {
            float4 w = wr4[j];
            #pragma unroll
            for (int rr = 0; rr < 4; ++rr) {
                float4 x = *reinterpret_cast<const float4*>(&emb_k[rh * 4 + rr][j * 4]);
                acc[rr] += w.x * x.x + w.y * x.y + w.z * x.z + w.w * x.w;
            }
        }
        float* kTrow = kprojT + ((size_t)b * E_ + e) * L_ + l0 + rh * 4;
        #pragma unroll
        for (int rr = 0; rr < 4; ++rr) kTrow[rr] = acc[rr];
    } else if (blk < 352) {
        // wotvh: packed bf16 pairs of value-channel columns.
        // c2 pairs channels (2c2, 2c2+1); col(c) = (c>>5)*64 + (c&31)
        int c20 = (blk - 320) * 4;
        #pragma unroll
        for (int j = 0; j < 4; ++j) {
            int c2 = c20 + j;
            int ca = 2 * c2, cb = 2 * c2 + 1;
            int cola = (ca >> 5) * 64 + (ca & 31);
            int colb = (cb >> 5) * 64 + (cb & 31);
            float a = wo[(size_t)t * 512 + cola];
            float b = wo[(size_t)t * 512 + colb];
            wotvh[(size_t)c2 * HID_ + t] = pack_bf2(a, b);
        }
    } else {
        // cvec[b][hid] = bo[hid] + sum_r cm[b][r] * wo[hid][h1*64+32+r]
        int b = blk - 352;
        if (t < D_) cm_s[t] = cm[b * D_ + t];
        __syncthreads();
        int hid = t;
        const float4* wrow4 = reinterpret_cast<const float4*>(wo + (size_t)hid * 512);
        float accm = 0.f;
        #pragma unroll
        for (int h1 = 0; h1 < 8; ++h1) {
            #pragma unroll
            for (int j = 0; j < 8; ++j) {
                float4 w = wrow4[h1 * 16 + 8 + j];
                accm += cm_s[j * 4 + 0] * w.x + cm_s[j * 4 + 1] * w.y
                      + cm_s[j * 4 + 2] * w.z + cm_s[j * 4 + 3] * w.w;
            }
        }
        cvec[b * HID_ + hid] = bo[hid] + accm;
    }
}

// ---------------------------------------------------------------------------
// k_main: 512 threads, TWO q rows per block (thread = (qi, t)); grid
//   (Q/2, B) = 512 blocks. Full LDS mvm staging.
//   Phase 1 (qi, l=t): s[h] via COALESCED kprojT columns (lane l consecutive);
//                      per-(qi,h) global max; e = exp(s - G).
//   Phase 2 (qi, lseg, h, d4): float4 accumulation, 64 l x 4 d; partials
//            alias e_s[qi]. Combine -> ctx_s[qi][256].
//   GEMM (qi, hid=t): bf16-packed wotvh + cvec. LN per row + pool.
// ---------------------------------------------------------------------------
__global__ __launch_bounds__(512, 4) void k_main(
    const float* __restrict__ qproj, const float* __restrict__ kprojT,
    const float* __restrict__ mvm, const unsigned* __restrict__ bitsT,
    const float* __restrict__ cm, const float* __restrict__ colmean,
    const unsigned* __restrict__ wotvh, const float* __restrict__ cvec,
    const float* __restrict__ has,
    const float* __restrict__ ln_g, const float* __restrict__ ln_b,
    float* __restrict__ seq_out, float* __restrict__ pooled)
{
    int qb = blockIdx.x, b = blockIdx.y;
    int tid = threadIdx.x;               // 0..511
    int qi = tid >> 8, t = tid & 255;
    __shared__ __align__(16) float mvm_s[L_ * D_];    // 32 KB
    __shared__ __align__(16) float e_s[2][L_ * H_];   // 16 KB; aliased for partials
    __shared__ __align__(16) float qv_s[2][E_];
    __shared__ unsigned bits_s[256];
    __shared__ float gmax_s[16];
    __shared__ __align__(16) float ctx_s[2][256];
    __shared__ float red_s[2][8];
    __shared__ float mu_rs[2][2];

    // stage: mvm (coalesced float4 by all 512), bits, qv per half
    {
        const float4* src = reinterpret_cast<const float4*>(mvm + (size_t)b * L_ * D_);
        float4* dst = reinterpret_cast<float4*>(mvm_s);
        #pragma unroll
        for (int j = 0; j < 4; ++j) dst[tid + j * 512] = src[tid + j * 512];
        if (qi == 0) bits_s[t] = bitsT[b * 256 + t];
        if (t < E_) qv_s[qi][t] = qproj[(qb * 2 + qi) * E_ + t];
    }
    __syncthreads();

    // Phase 1: thread (qi, l=t): scores for row qi. Coalesced kprojT reads:
    // lane t reads kT[(h*16+j)*L + t] -- 64 consecutive dwords per wave-instr.
    const float* kT = kprojT + (size_t)b * (E_ * L_);
    const float4* qv4 = reinterpret_cast<const float4*>(qv_s[qi]);
    float s[H_];
    #pragma unroll
    for (int h = 0; h < H_; ++h) {
        float4 q0 = qv4[h * 4 + 0], q1 = qv4[h * 4 + 1];
        float4 q2 = qv4[h * 4 + 2], q3 = qv4[h * 4 + 3];
        float qs[16] = {q0.x, q0.y, q0.z, q0.w, q1.x, q1.y, q1.z, q1.w,
                        q2.x, q2.y, q2.z, q2.w, q3.x, q3.y, q3.z, q3.w};
        const float* kcol = kT + (size_t)(h * 16) * L_ + t;
        float acc = 0.f;
        #pragma unroll
        for (int j = 0; j < 16; ++j)
            acc += kcol[(size_t)j * L_] * qs[j];
        s[h] = acc * 0.25f;                // 1/sqrt(EK=16)
    }
    {
        float4* er4 = reinterpret_cast<float4*>(&e_s[qi][t * 8]);
        er4[0] = *reinterpret_cast<float4*>(&s[0]);
        er4[1] = *reinterpret_cast<float4*>(&s[4]);
    }
    __syncthreads();
    // per-(qi,h) global max: 16 groups of 32 lanes
    {
        int g = tid >> 5, ln = tid & 31;
        int gq = g >> 3, h = g & 7;
        float mx = -1e30f;
        #pragma unroll
        for (int j = 0; j < 8; ++j) mx = fmaxf(mx, e_s[gq][(ln + j * 32) * 8 + h]);
        #pragma unroll
        for (int off = 16; off > 0; off >>= 1) mx = fmaxf(mx, __shfl_xor(mx, off));
        if (ln == 0) gmax_s[g] = mx;
    }
    __syncthreads();
    {
        float e8[H_];
        #pragma unroll
        for (int h = 0; h < H_; ++h) e8[h] = __expf(s[h] - gmax_s[qi * 8 + h]);
        float4* er4 = reinterpret_cast<float4*>(&e_s[qi][t * 8]);
        er4[0] = *reinterpret_cast<float4*>(&e8[0]);
        er4[1] = *reinterpret_cast<float4*>(&e8[4]);
    }
    __syncthreads();

    // Phase 2: thread (qi, lseg=t>>6, h=(t>>3)&7, d4=t&7); 64 l x 4 d
    {
        int lseg = t >> 6, h = (t >> 3) & 7, d4 = t & 7;
        unsigned w0[4], w1[4];
        #pragma unroll
        for (int j = 0; j < 4; ++j) {
            int d = d4 * 4 + j;
            w0[j] = bits_s[d * 8 + lseg * 2 + 0];
            w1[j] = bits_s[d * 8 + lseg * 2 + 1];
        }
        float4 av  = {0.f, 0.f, 0.f, 0.f};
        float4 den = {0.f, 0.f, 0.f, 0.f};
        const float4* mv4 = reinterpret_cast<const float4*>(mvm_s);
        const float* ep = e_s[qi];
        int l0 = lseg * 64;
        #pragma unroll 8
        for (int i = 0; i < 32; ++i) {
            int l = l0 + i;
            float e = ep[l * 8 + h];
            float4 m = mv4[l * 8 + d4];
            av.x += e * m.x; av.y += e * m.y; av.z += e * m.z; av.w += e * m.w;
            den.x += ((w0[0] >> i) & 1u) ? e : 0.f;
            den.y += ((w0[1] >> i) & 1u) ? e : 0.f;
            den.z += ((w0[2] >> i) & 1u) ? e : 0.f;
            den.w += ((w0[3] >> i) & 1u) ? e : 0.f;
        }
        #pragma unroll 8
        for (int i = 0; i < 32; ++i) {
            int l = l0 + 32 + i;
            float e = ep[l * 8 + h];
            float4 m = mv4[l * 8 + d4];
            av.x += e * m.x; av.y += e * m.y; av.z += e * m.z; av.w += e * m.w;
            den.x += ((w1[0] >> i) & 1u) ? e : 0.f;
            den.y += ((w1[1] >> i) & 1u) ? e : 0.f;
            den.z += ((w1[2] >> i) & 1u) ? e : 0.f;
            den.w += ((w1[3] >> i) & 1u) ? e : 0.f;
        }
        __syncthreads();                 // all e_s reads complete
        float4* p4 = reinterpret_cast<float4*>(e_s[qi]);   // alias: partials (8 KB/row)
        p4[t * 2 + 0] = av;
        p4[t * 2 + 1] = den;
    }
    __syncthreads();
    // combine: thread (qi, hh=t>>5, dd=t&31) writes ctx_s[qi][t]
    {
        const float* part = e_s[qi];
        int hh = t >> 5, dd = t & 31, dg = dd >> 2, jj = dd & 3;
        float a = 0.f, dn = 0.f;
        #pragma unroll
        for (int ls = 0; ls < 4; ++ls) {
            int pt = ls * 64 + hh * 8 + dg;
            a  += part[pt * 8 + jj];
            dn += part[pt * 8 + 4 + jj];
        }
        float cmf = cm[b * D_ + dd];
        ctx_s[qi][t] = (cmf > 0.f) ? (a / dn) : colmean[b * D_ + dd];
    }
    __syncthreads();

    // GEMM: thread (qi, hid=t); K = 256 value channels via bf16-packed wotvh
    int hid = t;
    float acc = cvec[b * HID_ + hid];
    #pragma unroll 8
    for (int c2 = 0; c2 < 128; ++c2) {
        unsigned u = wotvh[(size_t)c2 * HID_ + hid];
        float2 cc = *reinterpret_cast<const float2*>(&ctx_s[qi][c2 * 2]);
        float w0 = __uint_as_float(u << 16);          // bf16 -> f32 exact
        float w1 = __uint_as_float(u & 0xffff0000u);
        acc += cc.x * w0 + cc.y * w1;
    }

    // fused LayerNorm per row (waves 0-3 = row0, 4-7 = row1)
    int wave = tid >> 6;
    {
        float sum = acc, ssum = acc * acc;
        #pragma unroll
        for (int off = 32; off > 0; off >>= 1) {
            sum  += __shfl_xor(sum, off);
            ssum += __shfl_xor(ssum, off);
        }
        if ((tid & 63) == 0) {
            red_s[qi][wave & 3]       = sum;
            red_s[qi][4 + (wave & 3)] = ssum;
        }
    }
    __syncthreads();
    if (t == 0) {                        // tid 0 and 256: one per row
        float S  = red_s[qi][0] + red_s[qi][1] + red_s[qi][2] + red_s[qi][3];
        float SS = red_s[qi][4] + red_s[qi][5] + red_s[qi][6] + red_s[qi][7];
        float mu = S * (1.f / HID_);
        float var = SS * (1.f / HID_) - mu * mu;
        mu_rs[qi][0] = mu;
        mu_rs[qi][1] = rsqrtf(var + 1e-5f);
    }
    __syncthreads();

    float outv = ((acc - mu_rs[qi][0]) * mu_rs[qi][1] * ln_g[hid] + ln_b[hid]) * has[b];
    seq_out[((size_t)(b * Q_ + qb * 2 + qi)) * HID_ + hid] = outv;
    atomicAdd(&pooled[b * HID_ + hid], outv * (1.f / (float)Q_));
}

// ---------------------------------------------------------------------------
extern "C" void kernel_launch(void* const* d_in, const int* in_sizes, int n_in,
                              void* d_out, int out_size, void* d_ws, size_t ws_size,
                              hipStream_t stream)
{
    const float* values = (const float*)d_in[0];
    const int*   mask   = (const int*)  d_in[1];
    const float* times  = (const float*)d_in[2];
    const float* w_per  = (const float*)d_in[3];
    const float* b_per  = (const float*)d_in[4];
    const float* w_lin  = (const float*)d_in[5];
    const float* b_lin  = (const float*)d_in[6];
    const float* wq     = (const float*)d_in[7];
    const float* bq     = (const float*)d_in[8];
    const float* wk     = (const float*)d_in[9];
    const float* bk     = (const float*)d_in[10];
    const float* wo     = (const float*)d_in[11];
    const float* bo     = (const float*)d_in[12];
    const float* ln_g   = (const float*)d_in[13];
    const float* ln_b   = (const float*)d_in[14];

    float* out     = (float*)d_out;
    float* seq_out = out;                        // B*Q*HID = 262144
    float* pooled  = out + 262144;               // B*HID   = 2048
    float* qt_out  = out + 262144 + 2048;        // B*Q     = 1024

    float* ws         = (float*)d_ws;
    float*    tn      = ws;                      // 2048
    float*    has     = ws + 2048;               // 8
    float*    cm      = ws + 2056;               // 256
    float*    colmean = ws + 2312;               // 256
    float*    qproj   = ws + 2568;               // 16384  (byte 10272, 16B-aligned)
    unsigned* bitsT   = (unsigned*)(ws + 18952); // 2048 u32
    float*    mvm     = ws + 21000;              // 65536  (byte 84000, 16B-aligned)
    float*    kprojT  = ws + 86536;              // 262144 = B*E*L (byte 346144, 16B-aligned)
    float*    cvec    = ws + 348680;             // 2048
    unsigned* wotvh   = (unsigned*)(ws + 350728); // 32768 u32 -> end 1.53 MB

    k_prep1<<<B_,               256, 0, stream>>>(values, mask, times,
                 tn, has, cm, colmean, mvm, bitsT, qt_out, pooled);
    k_prep2<<<360,              256, 0, stream>>>(tn, cm, w_per, b_per, w_lin, b_lin,
                 wq, bq, wk, bk, wo, bo, qproj, kprojT, wotvh, cvec);
    k_main <<<dim3(Q_ / 2, B_), 512, 0, stream>>>(qproj, kprojT, mvm, bitsT,
                 cm, colmean, wotvh, cvec, has, ln_g, ln_b, seq_out, pooled);
}